// Round 21
// baseline (327.923 us; speedup 1.0000x reference)
//
#include <hip/hip_runtime.h>

typedef short s16x4 __attribute__((ext_vector_type(4)));
typedef short s16x8 __attribute__((ext_vector_type(8)));
typedef float f32x4 __attribute__((ext_vector_type(4)));
typedef unsigned u32x4 __attribute__((ext_vector_type(4)));
typedef unsigned short u16;
typedef unsigned char u8;

__device__ __forceinline__ u16 f2b(float f) {
    union { float f; unsigned u; } v; v.f = f;
    unsigned r = v.u + 0x7FFFu + ((v.u >> 16) & 1u);
    return (u16)(r >> 16);
}

__device__ __forceinline__ float fexp2(float x) {
    float r; asm("v_exp_f32 %0, %1" : "=v"(r) : "v"(x)); return r;
}

__device__ __forceinline__ unsigned cvtpk(float lo, float hi) {
    unsigned r; asm("v_cvt_pk_bf16_f32 %0, %1, %2" : "=v"(r) : "v"(lo), "v"(hi)); return r;
}

__device__ __forceinline__ void GLL(const void* g, void* l) {
    __builtin_amdgcn_global_load_lds(
        (const __attribute__((address_space(1))) unsigned int*)g,
        (__attribute__((address_space(3))) unsigned int*)l, 16, 0, 0);
}

// explicit DMA drain before barriers that publish staged LDS (R6/R7 race evidence)
__device__ __forceinline__ void vmwait0() {
    asm volatile("s_waitcnt vmcnt(0)" ::: "memory");
    __builtin_amdgcn_sched_barrier(0);
}

// Q pre-scale: hd^-0.5 * log2(e) so attention uses v_exp_f32 (2^x) directly
#define QSCALE 0.1803368801111244f

// ---------------- fused prolog: castgate (blocks 0..2047) + wcast (blocks 2048..4351) ----------------
__global__ __launch_bounds__(256) void prolog_kernel(const float* __restrict__ x,
                                                     const float* __restrict__ Wg,
                                                     u16* __restrict__ xb,
                                                     u8* __restrict__ kArr,
                                                     float* __restrict__ out,
                                                     const float* __restrict__ W0,
                                                     const float* __restrict__ W1,
                                                     const float* __restrict__ W2,
                                                     const float* __restrict__ W3,
                                                     const float* __restrict__ W4,
                                                     const float* __restrict__ W5,
                                                     u16* __restrict__ wqt,
                                                     u16* __restrict__ wpt) {
    __shared__ u16 tile[32][34];
    if (blockIdx.x < 2048) {
        int t = blockIdx.x * 4 + (threadIdx.x >> 6);
        int lane = threadIdx.x & 63;
        const float* xr = x + (size_t)t * 768;
        u16* xw = xb + (size_t)t * 768;
        float z0 = 0.f, z1 = 0.f, z2 = 0.f;
        #pragma unroll
        for (int s = 0; s < 3; s++) {
            int base = s * 256 + lane * 4;
            f32x4 v = *(const f32x4*)(xr + base);
            s16x4 o;
            #pragma unroll
            for (int j = 0; j < 4; j++) {
                o[j] = (short)f2b(v[j]);
                z0 = fmaf(v[j], Wg[(base + j) * 3 + 0], z0);
                z1 = fmaf(v[j], Wg[(base + j) * 3 + 1], z1);
                z2 = fmaf(v[j], Wg[(base + j) * 3 + 2], z2);
            }
            *(s16x4*)(xw + base) = o;
        }
        for (int o = 32; o; o >>= 1) {
            z0 += __shfl_xor(z0, o);
            z1 += __shfl_xor(z1, o);
            z2 += __shfl_xor(z2, o);
        }
        if (lane == 0) {
            int k = 0; float b = z0;
            if (z1 > b) { b = z1; k = 1; }
            if (z2 > b) { b = z2; k = 2; }
            out[12582912 + t] = (float)k;   // idx output
            kArr[t] = (u8)k;
        }
    } else {
        int wb = blockIdx.x - 2048;          // 0..2303
        int y, bt;
        if (wb < 1728) { y = wb / 576; bt = wb % 576; }
        else           { int w2 = wb - 1728; y = 3 + w2 / 192; bt = w2 % 192; }
        const float* W; u16* dst; int K;
        if (y < 3) { W = (y == 0) ? W0 : (y == 1) ? W1 : W2; dst = wqt + y * 589824; K = 768; }
        else       { W = (y == 3) ? W3 : (y == 4) ? W4 : W5; dst = wpt + (y - 3) * 196608; K = 256; }
        int ktiles = K >> 5;
        int kt = bt % ktiles, nt = bt / ktiles;
        int tx = threadIdx.x & 31, ty = threadIdx.x >> 5;
        #pragma unroll
        for (int i = 0; i < 4; i++) {
            int k = kt * 32 + ty + i * 8;
            tile[ty + i * 8][tx] = f2b(W[(size_t)k * 768 + nt * 32 + tx]);
        }
        __syncthreads();
        #pragma unroll
        for (int i = 0; i < 4; i++) {
            int n = nt * 32 + ty + i * 8;
            dst[(size_t)n * K + kt * 32 + tx] = tile[tx][ty + i * 8];
        }
    }
}

// ---------------- compact v3: flags preloaded to registers, 96 register ballots ----------------
__global__ __launch_bounds__(64) void compact_kernel(const u8* __restrict__ kArr,
                                                     u16* __restrict__ perm,
                                                     int* __restrict__ cnt,
                                                     int* __restrict__ startA) {
    int batch = blockIdx.x;
    int lane = threadIdx.x;
    const u8* ka = kArr + batch * 2048;
    u8 kv[32];
    #pragma unroll
    for (int i = 0; i < 32; i++) kv[i] = ka[i * 64 + lane];
    u16* pm = perm + batch * 2048;
    int off = 0;
    for (int br = 0; br < 3; br++) {
        int c = 0;
        #pragma unroll
        for (int i = 0; i < 32; i++) {
            bool p = (kv[i] == (u8)br);
            unsigned long long m = __ballot(p);
            int rank = __popcll(m & ((1ull << lane) - 1ull));
            if (p) pm[off + c + rank] = (u16)(i * 64 + lane);
            c += __popcll(m);
        }
        if (lane == 0) { cnt[br * 4 + batch] = c; startA[br * 4 + batch] = off; }
        off += c;
    }
}

// ---------------- QKV GEMM: 256x256 tile, 8 waves, SERIAL GLL staging (R15-proven schedule) ----------------
// Bisection of R20's NaN: keep the 256^2 geometry (2x arithmetic intensity vs the measured
// delivery bound), revert the loop to barrier -> stage -> drain -> barrier -> compute.
__global__ __launch_bounds__(512) void qkv_gemm_kernel(const u16* __restrict__ A,
                                                       const u16* __restrict__ Bt_all,
                                                       const u16* __restrict__ perm,
                                                       const int* __restrict__ cnt,
                                                       const int* __restrict__ startA,
                                                       u16* __restrict__ Qo,
                                                       u16* __restrict__ Ko,
                                                       u16* __restrict__ Vt) {
    __shared__ u16 As[256 * 64];
    __shared__ u16 Bs[256 * 64];
    const int tid = threadIdx.x;
    const int lane = tid & 63, w = tid >> 6;        // 8 waves
    const int wm = w >> 2, wn = w & 3;              // 2m x 4n wave grid
    const int g = lane >> 4, c15 = lane & 15;
    const int cx = c15 & 7;
    const int b = blockIdx.x;
    const int j = b >> 3;                           // 0..35
    const int v = j % 9;
    const int branch = v / 3;
    const int m0 = ((b & 7) * 4 + j / 9) * 256;     // XCD-pinned m-panel
    const int n0 = (v % 3) * 256;
    const u16* Bt = Bt_all + (size_t)branch * 589824;

    const int l8 = lane >> 3;
    const int ch = (lane & 7) ^ l8;                 // chunk involution (64B rows)
    const int batch0 = m0 >> 11, pbase = m0 & 2047;
    const u16* Arow[4];
    if (n0 == 0) {
        // all-Q tile: compacted rows (masked gather -> garbage-impossible)
        const int cb = branch * 4 + batch0;
        const int count = min(2048, cnt[cb]);
        if (pbase >= count) return;
        const u16* ci = perm + batch0 * 2048 + startA[cb];
        #pragma unroll
        for (int it = 0; it < 4; it++) {
            int slot = pbase + w * 32 + l8 + it * 8;
            int tok = ci[slot < count ? slot : count - 1] & 2047;
            Arow[it] = A + (size_t)(batch0 * 2048 + tok) * 768 + ch * 8;
        }
    } else {
        #pragma unroll
        for (int it = 0; it < 4; it++)
            Arow[it] = A + (size_t)(m0 + w * 32 + l8 + it * 8) * 768 + ch * 8;
    }
    const u16* Bsrc = Bt + (size_t)(n0 + w * 32 + l8) * 768 + ch * 8;
    u16* AsW = As + w * 2048;
    u16* BsW = Bs + w * 2048;

    f32x4 z4 = {0.f, 0.f, 0.f, 0.f};
    f32x4 acc[8][4];
    for (int mi = 0; mi < 8; mi++)
        for (int ni = 0; ni < 4; ni++) acc[mi][ni] = z4;

    for (int k0 = 0; k0 < 768; k0 += 64) {
        __syncthreads();
        #pragma unroll
        for (int it = 0; it < 4; it++) {
            GLL(Arow[it] + k0, AsW + it * 512);
            GLL(Bsrc + (size_t)(it * 8) * 768 + k0, BsW + it * 512);
        }
        vmwait0();
        __syncthreads();
        #pragma unroll
        for (int kk = 0; kk < 2; kk++) {
            s16x8 af[8], bf[4];
            #pragma unroll
            for (int i = 0; i < 8; i++)
                af[i] = *(const s16x8*)&As[(wm * 128 + i * 16 + c15) * 64 + (((kk * 4 + g) ^ cx) * 8)];
            #pragma unroll
            for (int i = 0; i < 4; i++)
                bf[i] = *(const s16x8*)&Bs[(wn * 64 + i * 16 + c15) * 64 + (((kk * 4 + g) ^ cx) * 8)];
            for (int mi = 0; mi < 8; mi++)
                for (int ni = 0; ni < 4; ni++)
                    acc[mi][ni] = __builtin_amdgcn_mfma_f32_16x16x32_bf16(
                        af[mi], bf[ni], acc[mi][ni], 0, 0, 0);
        }
    }

    for (int mi = 0; mi < 8; mi++) {
        int r = m0 + wm * 128 + mi * 16 + g * 4;
        int batch = r >> 11, nbase = r & 2047;   // nbase = slot for Q tiles
        for (int ni = 0; ni < 4; ni++) {
            int cN = n0 + wn * 64 + ni * 16 + c15;
            int p = cN >> 8, h = (cN >> 6) & 3, d = cN & 63;
            size_t hb = (size_t)((branch * 4 + batch) * 4 + h) * 131072;
            f32x4 vv = acc[mi][ni];
            if (p == 2) {
                s16x4 pk;
                for (int rg = 0; rg < 4; rg++) pk[rg] = (short)f2b(vv[rg]);
                int pos = nbase & 31;
                int slot = ((pos & 15) >> 2) * 8 + ((pos >> 4) << 2);
                *(s16x4*)(Vt + hb + (size_t)d * 2048 + (nbase & ~31) + slot) = pk;
            } else if (p == 0) {
                for (int rg = 0; rg < 4; rg++)
                    Qo[hb + (size_t)(nbase + rg) * 64 + d] = f2b(vv[rg] * QSCALE);
            } else {
                for (int rg = 0; rg < 4; rg++)
                    Ko[hb + (size_t)(nbase + rg) * 64 + d] = f2b(vv[rg]);
            }
        }
    }
}

// ---------------- flash attention (R15-proven): slot-direct Q, LDS-staged K/V, + T5 setprio ----------------
#define ATTN_STEP(KF, VF) do {                                                              \
    __builtin_amdgcn_s_setprio(1);                                                          \
    _Pragma("unroll")                                                                       \
    for (int s = 0; s < 2; s++) {                                                           \
        f32x4 sa0 = __builtin_amdgcn_mfma_f32_16x16x32_bf16(KF[0][0], qf[s][0], z4, 0, 0, 0); \
        sa0 = __builtin_amdgcn_mfma_f32_16x16x32_bf16(KF[0][1], qf[s][1], sa0, 0, 0, 0);    \
        f32x4 sa1 = __builtin_amdgcn_mfma_f32_16x16x32_bf16(KF[1][0], qf[s][0], z4, 0, 0, 0); \
        sa1 = __builtin_amdgcn_mfma_f32_16x16x32_bf16(KF[1][1], qf[s][1], sa1, 0, 0, 0);    \
        float q0 = fexp2(sa0[0]), q1 = fexp2(sa0[1]);                                       \
        float q2 = fexp2(sa0[2]), q3 = fexp2(sa0[3]);                                       \
        float q4 = fexp2(sa1[0]), q5 = fexp2(sa1[1]);                                       \
        float q6 = fexp2(sa1[2]), q7 = fexp2(sa1[3]);                                       \
        lsp[s] += ((q0 + q1) + (q2 + q3)) + ((q4 + q5) + (q6 + q7));                        \
        u32x4 pw;                                                                           \
        pw[0] = cvtpk(q0, q1); pw[1] = cvtpk(q2, q3);                                       \
        pw[2] = cvtpk(q4, q5); pw[3] = cvtpk(q6, q7);                                       \
        union { u32x4 w; s16x8 h; } pu; pu.w = pw;                                          \
        s16x8 pb = pu.h;                                                                    \
        _Pragma("unroll")                                                                   \
        for (int dt = 0; dt < 4; dt++)                                                      \
            oac[s][dt] = __builtin_amdgcn_mfma_f32_16x16x32_bf16(VF[dt], pb, oac[s][dt], 0, 0, 0); \
    }                                                                                       \
    __builtin_amdgcn_s_setprio(0);                                                          \
} while (0)

#define STAGE(B, T) do {                                                  \
    const unsigned char* _ks = Ksrc + (size_t)(T) * 8192;                 \
    const unsigned char* _vs = Vsrc + (size_t)(T) * 128;                  \
    unsigned char* _kd = &lds[(B) * 16384 + w * 2048];                    \
    unsigned char* _vd = &lds[(B) * 16384 + 8192 + w * 2048];             \
    GLL(_ks, _kd); GLL(_ks + 1024, _kd + 1024);                           \
    GLL(_vs, _vd); GLL(_vs + 32768, _vd + 1024);                          \
} while (0)

#define TILE_STEP(B) do {                                                               \
    const unsigned char* _KL = &lds[(B) * 16384];                                       \
    const unsigned char* _VL = &lds[(B) * 16384 + 8192];                                \
    s16x8 kf[2][2], vf[4];                                                              \
    _Pragma("unroll")                                                                   \
    for (int t = 0; t < 2; t++)                                                         \
        _Pragma("unroll")                                                               \
        for (int h = 0; h < 2; h++)                                                     \
            kf[t][h] = *(const s16x8*)(_KL + (t * 16 + c) * 128 + (((h * 4 + g) ^ cx) * 16)); \
    _Pragma("unroll")                                                                   \
    for (int dt = 0; dt < 4; dt++)                                                      \
        vf[dt] = *(const s16x8*)(_VL + (dt * 16 + c) * 128 + ((g ^ cx) * 16));          \
    ATTN_STEP(kf, vf);                                                                  \
    _Pragma("unroll")                                                                   \
    for (int t = 0; t < 2; t++)                                                         \
        _Pragma("unroll")                                                               \
        for (int h = 0; h < 2; h++)                                                     \
            kf[t][h] = *(const s16x8*)(_KL + ((t + 2) * 16 + c) * 128 + (((h * 4 + g) ^ cx) * 16)); \
    _Pragma("unroll")                                                                   \
    for (int dt = 0; dt < 4; dt++)                                                      \
        vf[dt] = *(const s16x8*)(_VL + (dt * 16 + c) * 128 + (((4 + g) ^ cx) * 16));    \
    ATTN_STEP(kf, vf);                                                                  \
} while (0)

__global__ __launch_bounds__(256, 4) void attn_kernel(const u16* __restrict__ Qg,
                                                      const u16* __restrict__ Kg,
                                                      const u16* __restrict__ Vg,
                                                      const int* __restrict__ cnt,
                                                      u16* __restrict__ Og) {
    __shared__ unsigned char lds[32768];
    const int tid = threadIdx.x;
    const int w = tid >> 6, lane = tid & 63;
    const int b = blockIdx.x;
    const int j = b >> 3;
    const int inst = (b & 7) * 6 + (j % 6);   // XCD-pinned instance
    const int branch = inst >> 4, batch = (inst >> 2) & 3, h = inst & 3;
    const int cb = branch * 4 + batch;
    const int count = min(2048, cnt[cb]);
    const int qbase = (j / 6) * 128;
    if (qbase >= count) return;               // uniform whole-block exit
    const int qt = (j / 6) * 4 + w;           // q-tile of 32 compacted slots
    const int g = lane >> 4, c = lane & 15;
    const int cx = c & 7;
    const u16* Qh = Qg + (size_t)inst * 131072;

    f32x4 z4 = {0.f, 0.f, 0.f, 0.f};
    s16x8 qf[2][2];
    #pragma unroll
    for (int kk = 0; kk < 2; kk++) {
        qf[0][kk] = *(const s16x8*)(Qh + (size_t)(qt * 32 + c) * 64 + kk * 32 + g * 8);
        qf[1][kk] = *(const s16x8*)(Qh + (size_t)(qt * 32 + 16 + c) * 64 + kk * 32 + g * 8);
    }

    f32x4 oac[2][4];
    #pragma unroll
    for (int s = 0; s < 2; s++)
        #pragma unroll
        for (int dt = 0; dt < 4; dt++) oac[s][dt] = z4;
    float lsp[2] = {0.f, 0.f};

    const int swz = (((lane & 7) ^ ((lane >> 3) & 7)) << 4);
    const unsigned char* Ksrc = (const unsigned char*)(Kg + (size_t)inst * 131072)
                                + w * 2048 + ((lane >> 3) << 7) + swz;
    const unsigned char* Vsrc = (const unsigned char*)(Vg + (size_t)inst * 131072)
                                + (size_t)w * 65536 + ((lane >> 3) << 12) + swz;

    STAGE(0, 0);
    vmwait0();
    __syncthreads();
    for (int t2 = 0; t2 < 32; t2++) {
        int cur = t2 & 1;
        if (t2 + 1 < 32) STAGE(cur ^ 1, t2 + 1);
        TILE_STEP(cur);
        vmwait0();
        __syncthreads();
    }

    // write ALL 128 slots of this block (slots >= count hold duplicated real rows)
    #pragma unroll
    for (int s = 0; s < 2; s++) {
        float ls = lsp[s];
        ls += __shfl_xor(ls, 16);
        ls += __shfl_xor(ls, 32);
        float inv = 1.0f / ls;
        int slot = qt * 32 + s * 16 + c;
        u16* dst = Og + ((size_t)cb * 2048 + slot) * 256 + h * 64;
        #pragma unroll
        for (int dt = 0; dt < 4; dt++) {
            s16x4 ob;
            for (int rg = 0; rg < 4; rg++) ob[rg] = (short)f2b(oac[s][dt][rg] * inv);
            *(s16x4*)(dst + dt * 16 + g * 4) = ob;
        }
    }
}

// ---------------- proj GEMM: contiguous compacted rows, masked scatter ----------------
__global__ __launch_bounds__(256) void proj_gemm_kernel(const u16* __restrict__ Oall,
                                                        const u16* __restrict__ Wpt_all,
                                                        const u16* __restrict__ perm,
                                                        const int* __restrict__ cnt,
                                                        const int* __restrict__ startA,
                                                        const float* __restrict__ bp1,
                                                        const float* __restrict__ bp2,
                                                        const float* __restrict__ bp3,
                                                        float* __restrict__ out) {
    __shared__ u16 As[128 * 64];
    __shared__ u16 Bs[128 * 64];
    const int tid = threadIdx.x;
    const int lane = tid & 63, w = tid >> 6, wm = w >> 1, wn = w & 1;
    const int g = lane >> 4, c15 = lane & 15;
    const int cx = c15 & 7;
    const int branch = blockIdx.z;
    const int m0 = blockIdx.y * 128, n0 = blockIdx.x * 128;
    const int batch = m0 >> 11;
    const int cb = branch * 4 + batch;
    const int count = min(2048, cnt[cb]);
    const int pbase = m0 & 2047;
    if (pbase >= count) return;
    const u16* A = Oall + (size_t)branch * 8192 * 256;
    const u16* Bt = Wpt_all + (size_t)branch * 196608;
    const float* bp = (branch == 0) ? bp1 : ((branch == 1) ? bp2 : bp3);

    const int l8 = lane >> 3;
    const int ch = (lane & 7) ^ l8;
    const u16* Asrc = A + (size_t)(m0 + w * 32 + l8) * 256 + ch * 8;
    const u16* Bsrc = Bt + (size_t)(n0 + w * 32 + l8) * 256 + ch * 8;
    u16* AsW = As + w * 2048;
    u16* BsW = Bs + w * 2048;

    f32x4 z4 = {0.f, 0.f, 0.f, 0.f};
    f32x4 acc[4][4];
    for (int mi = 0; mi < 4; mi++)
        for (int ni = 0; ni < 4; ni++) acc[mi][ni] = z4;

    for (int k0 = 0; k0 < 256; k0 += 64) {
        __syncthreads();
        #pragma unroll
        for (int it = 0; it < 4; it++) {
            GLL(Asrc + (size_t)(it * 8) * 256 + k0, AsW + it * 512);
            GLL(Bsrc + (size_t)(it * 8) * 256 + k0, BsW + it * 512);
        }
        vmwait0();
        __syncthreads();
        #pragma unroll
        for (int kk = 0; kk < 2; kk++) {
            s16x8 af[4], bf[4];
            #pragma unroll
            for (int i = 0; i < 4; i++) {
                af[i] = *(const s16x8*)&As[(wm * 64 + i * 16 + c15) * 64 + (((kk * 4 + g) ^ cx) * 8)];
                bf[i] = *(const s16x8*)&Bs[(wn * 64 + i * 16 + c15) * 64 + (((kk * 4 + g) ^ cx) * 8)];
            }
            for (int mi = 0; mi < 4; mi++)
                for (int ni = 0; ni < 4; ni++)
                    acc[mi][ni] = __builtin_amdgcn_mfma_f32_16x16x32_bf16(
                        af[mi], bf[ni], acc[mi][ni], 0, 0, 0);
        }
    }

    const u16* ci = perm + batch * 2048 + startA[cb];
    for (int mi = 0; mi < 4; mi++) {
        int r = pbase + wm * 64 + mi * 16 + g * 4;
        for (int ni = 0; ni < 4; ni++) {
            int cN = n0 + wn * 64 + ni * 16 + c15;
            float bj = bp[cN];
            f32x4 v = acc[mi][ni];
            for (int rg = 0; rg < 4; rg++) {
                int slot = r + rg;
                if (slot < count) {
                    int t = batch * 2048 + (ci[slot] & 2047);
                    float wv = v[rg] + bj;
                    out[(size_t)t * 768 + cN] = wv;                 // xo
                    out[6291456u + (size_t)t * 768 + cN] = wv;      // xd
                }
            }
        }
    }
}

extern "C" void kernel_launch(void* const* d_in, const int* in_sizes, int n_in,
                              void* d_out, int out_size, void* d_ws, size_t ws_size,
                              hipStream_t stream) {
    const float* x   = (const float*)d_in[0];
    const float* Wq1 = (const float*)d_in[1];
    const float* Wq2 = (const float*)d_in[2];
    const float* Wq3 = (const float*)d_in[3];
    const float* Wp1 = (const float*)d_in[4];
    const float* bp1 = (const float*)d_in[5];
    const float* Wp2 = (const float*)d_in[6];
    const float* bp2 = (const float*)d_in[7];
    const float* Wp3 = (const float*)d_in[8];
    const float* bp3 = (const float*)d_in[9];
    const float* Wg  = (const float*)d_in[10];
    float* out = (float*)d_out;

    char* ws = (char*)d_ws;
    u16* xb    = (u16*)(ws + 0);          // 12582912 B
    u16* wqt   = (u16*)(ws + 12582912);   // 3538944 B
    u16* wpt   = (u16*)(ws + 16121856);   // 1179648 B
    u16* Qb    = (u16*)(ws + 17301504);   // 12582912 B (48 x [2048 slots][64], pre-scaled, compacted)
    u16* Kb    = (u16*)(ws + 29884416);   // 12582912 B
    u16* Vtb   = (u16*)(ws + 42467328);   // 12582912 B (48 x [64][2048], slot-remapped)
    u16* Ob    = (u16*)(ws + 55050240);   // 12582912 B (12 x [2048][256], compacted rows)
    u16* perm  = (u16*)(ws + 67633152);   // 16384 B (4 x 2048 u16)
    int* cnt   = (int*)(ws + 67649536);   // 48 B
    int* start = (int*)(ws + 67649600);   // 48 B
    u8*  kArr  = (u8*) (ws + 67649664);   // 8192 B  -> end 67657856

    prolog_kernel<<<4352, 256, 0, stream>>>(x, Wg, xb, kArr, out,
                                            Wq1, Wq2, Wq3, Wp1, Wp2, Wp3, wqt, wpt);
    compact_kernel<<<4, 64, 0, stream>>>(kArr, perm, cnt, start);
    qkv_gemm_kernel<<<288, 512, 0, stream>>>(xb, wqt, perm, cnt, start, Qb, Kb, Vtb);
    attn_kernel<<<768, 256, 0, stream>>>(Qb, Kb, Vtb, cnt, Ob);
    proj_gemm_kernel<<<dim3(6, 64, 3), 256, 0, stream>>>(Ob, wpt, perm, cnt, start, bp1, bp2, bp3, out);
}

// Round 22
// 122.220 us; speedup vs baseline: 2.6831x; 2.6831x over previous
//
#include <hip/hip_runtime.h>

typedef short s16x4 __attribute__((ext_vector_type(4)));
typedef short s16x8 __attribute__((ext_vector_type(8)));
typedef float f32x4 __attribute__((ext_vector_type(4)));
typedef unsigned u32x4 __attribute__((ext_vector_type(4)));
typedef unsigned short u16;
typedef unsigned char u8;

__device__ __forceinline__ u16 f2b(float f) {
    union { float f; unsigned u; } v; v.f = f;
    unsigned r = v.u + 0x7FFFu + ((v.u >> 16) & 1u);
    return (u16)(r >> 16);
}

__device__ __forceinline__ float fexp2(float x) {
    float r; asm("v_exp_f32 %0, %1" : "=v"(r) : "v"(x)); return r;
}

__device__ __forceinline__ unsigned cvtpk(float lo, float hi) {
    unsigned r; asm("v_cvt_pk_bf16_f32 %0, %1, %2" : "=v"(r) : "v"(lo), "v"(hi)); return r;
}

__device__ __forceinline__ void GLL(const void* g, void* l) {
    __builtin_amdgcn_global_load_lds(
        (const __attribute__((address_space(1))) unsigned int*)g,
        (__attribute__((address_space(3))) unsigned int*)l, 16, 0, 0);
}

// explicit DMA drain before barriers that publish staged LDS (R6/R7 race evidence)
__device__ __forceinline__ void vmwait0() {
    asm volatile("s_waitcnt vmcnt(0)" ::: "memory");
    __builtin_amdgcn_sched_barrier(0);
}

// Q pre-scale: hd^-0.5 * log2(e) so attention uses v_exp_f32 (2^x) directly
#define QSCALE 0.1803368801111244f

// ---------------- fused prolog: castgate (blocks 0..2047) + wcast (blocks 2048..4351) ----------------
__global__ __launch_bounds__(256) void prolog_kernel(const float* __restrict__ x,
                                                     const float* __restrict__ Wg,
                                                     u16* __restrict__ xb,
                                                     u8* __restrict__ kArr,
                                                     float* __restrict__ out,
                                                     const float* __restrict__ W0,
                                                     const float* __restrict__ W1,
                                                     const float* __restrict__ W2,
                                                     const float* __restrict__ W3,
                                                     const float* __restrict__ W4,
                                                     const float* __restrict__ W5,
                                                     u16* __restrict__ wqt,
                                                     u16* __restrict__ wpt) {
    __shared__ u16 tile[32][34];
    if (blockIdx.x < 2048) {
        int t = blockIdx.x * 4 + (threadIdx.x >> 6);
        int lane = threadIdx.x & 63;
        const float* xr = x + (size_t)t * 768;
        u16* xw = xb + (size_t)t * 768;
        float z0 = 0.f, z1 = 0.f, z2 = 0.f;
        #pragma unroll
        for (int s = 0; s < 3; s++) {
            int base = s * 256 + lane * 4;
            f32x4 v = *(const f32x4*)(xr + base);
            s16x4 o;
            #pragma unroll
            for (int j = 0; j < 4; j++) {
                o[j] = (short)f2b(v[j]);
                z0 = fmaf(v[j], Wg[(base + j) * 3 + 0], z0);
                z1 = fmaf(v[j], Wg[(base + j) * 3 + 1], z1);
                z2 = fmaf(v[j], Wg[(base + j) * 3 + 2], z2);
            }
            *(s16x4*)(xw + base) = o;
        }
        for (int o = 32; o; o >>= 1) {
            z0 += __shfl_xor(z0, o);
            z1 += __shfl_xor(z1, o);
            z2 += __shfl_xor(z2, o);
        }
        if (lane == 0) {
            int k = 0; float b = z0;
            if (z1 > b) { b = z1; k = 1; }
            if (z2 > b) { b = z2; k = 2; }
            out[12582912 + t] = (float)k;   // idx output
            kArr[t] = (u8)k;
        }
    } else {
        int wb = blockIdx.x - 2048;          // 0..2303
        int y, bt;
        if (wb < 1728) { y = wb / 576; bt = wb % 576; }
        else           { int w2 = wb - 1728; y = 3 + w2 / 192; bt = w2 % 192; }
        const float* W; u16* dst; int K;
        if (y < 3) { W = (y == 0) ? W0 : (y == 1) ? W1 : W2; dst = wqt + y * 589824; K = 768; }
        else       { W = (y == 3) ? W3 : (y == 4) ? W4 : W5; dst = wpt + (y - 3) * 196608; K = 256; }
        int ktiles = K >> 5;
        int kt = bt % ktiles, nt = bt / ktiles;
        int tx = threadIdx.x & 31, ty = threadIdx.x >> 5;
        #pragma unroll
        for (int i = 0; i < 4; i++) {
            int k = kt * 32 + ty + i * 8;
            tile[ty + i * 8][tx] = f2b(W[(size_t)k * 768 + nt * 32 + tx]);
        }
        __syncthreads();
        #pragma unroll
        for (int i = 0; i < 4; i++) {
            int n = nt * 32 + ty + i * 8;
            dst[(size_t)n * K + kt * 32 + tx] = tile[tx][ty + i * 8];
        }
    }
}

// ---------------- compact v3: flags preloaded to registers, 96 register ballots ----------------
__global__ __launch_bounds__(64) void compact_kernel(const u8* __restrict__ kArr,
                                                     u16* __restrict__ perm,
                                                     int* __restrict__ cnt,
                                                     int* __restrict__ startA) {
    int batch = blockIdx.x;
    int lane = threadIdx.x;
    const u8* ka = kArr + batch * 2048;
    u8 kv[32];
    #pragma unroll
    for (int i = 0; i < 32; i++) kv[i] = ka[i * 64 + lane];
    u16* pm = perm + batch * 2048;
    int off = 0;
    for (int br = 0; br < 3; br++) {
        int c = 0;
        #pragma unroll
        for (int i = 0; i < 32; i++) {
            bool p = (kv[i] == (u8)br);
            unsigned long long m = __ballot(p);
            int rank = __popcll(m & ((1ull << lane) - 1ull));
            if (p) pm[off + c + rank] = (u16)(i * 64 + lane);
            c += __popcll(m);
        }
        if (lane == 0) { cnt[br * 4 + batch] = c; startA[br * 4 + batch] = off; }
        off += c;
    }
}

// ---------------- QKV GEMM: BK=32 double-buffered GLL, corrected (row>>1)&3 swizzle ----------------
#define QKV_STAGE(BUF, K0) do {                              \
    GLL(srcA0 + (K0), &As[BUF][w * 1024]);                   \
    GLL(srcA1 + (K0), &As[BUF][w * 1024 + 512]);             \
    GLL(srcB0 + (K0), &Bs[BUF][w * 1024]);                   \
    GLL(srcB1 + (K0), &Bs[BUF][w * 1024 + 512]);             \
} while (0)

__global__ __launch_bounds__(256) void qkv_gemm_kernel(const u16* __restrict__ A,
                                                       const u16* __restrict__ Bt_all,
                                                       const u16* __restrict__ perm,
                                                       const int* __restrict__ cnt,
                                                       const int* __restrict__ startA,
                                                       u16* __restrict__ Qo,
                                                       u16* __restrict__ Ko,
                                                       u16* __restrict__ Vt) {
    __shared__ u16 As[2][4096];
    __shared__ u16 Bs[2][4096];
    const int tid = threadIdx.x;
    const int lane = tid & 63, w = tid >> 6, wm = w >> 1, wn = w & 1;
    const int g = lane >> 4, c15 = lane & 15;
    const int cr = (c15 >> 1) & 3;            // read-side swizzle bits
    const int b = blockIdx.x;
    const int j = b >> 3;
    const int v = j % 18;
    const int branch = v / 6;
    const int m0 = ((b & 7) * 8 + j / 18) * 128;
    const int n0 = (v % 6) * 128;
    const u16* Bt = Bt_all + (size_t)branch * 589824;

    const int l4 = lane >> 2;                        // row within 16-row group
    const int ch = (lane & 3) ^ ((lane >> 3) & 3);   // source chunk: (l&3) ^ ((row>>1)&3)
    const int batch0 = m0 >> 11, pbase = m0 & 2047;
    const u16 *srcA0, *srcA1;
    if (n0 < 256) {
        const int cb = branch * 4 + batch0;
        const int count = min(2048, cnt[cb]);
        if (pbase >= count) return;
        const u16* ci = perm + batch0 * 2048 + startA[cb];
        int s0 = pbase + w * 32 + l4;      if (s0 >= count) s0 = count - 1;
        int s1 = pbase + w * 32 + 16 + l4; if (s1 >= count) s1 = count - 1;
        srcA0 = A + (size_t)(batch0 * 2048 + (ci[s0] & 2047)) * 768 + ch * 8;
        srcA1 = A + (size_t)(batch0 * 2048 + (ci[s1] & 2047)) * 768 + ch * 8;
    } else {
        srcA0 = A + (size_t)(m0 + w * 32 + l4) * 768 + ch * 8;
        srcA1 = A + (size_t)(m0 + w * 32 + 16 + l4) * 768 + ch * 8;
    }
    const u16* srcB0 = Bt + (size_t)(n0 + w * 32 + l4) * 768 + ch * 8;
    const u16* srcB1 = Bt + (size_t)(n0 + w * 32 + 16 + l4) * 768 + ch * 8;

    f32x4 z4 = {0.f, 0.f, 0.f, 0.f};
    f32x4 acc[4][4];
    for (int mi = 0; mi < 4; mi++)
        for (int ni = 0; ni < 4; ni++) acc[mi][ni] = z4;

    QKV_STAGE(0, 0);
    vmwait0();
    __syncthreads();
    for (int st = 0; st < 24; st++) {
        int cur = st & 1;
        if (st + 1 < 24) QKV_STAGE(cur ^ 1, (st + 1) * 32);   // issue next first
        {
            s16x8 af[4], bf[4];
            #pragma unroll
            for (int i = 0; i < 4; i++) {
                af[i] = *(const s16x8*)&As[cur][(wm * 64 + i * 16 + c15) * 32 + ((g ^ cr) * 8)];
                bf[i] = *(const s16x8*)&Bs[cur][(wn * 64 + i * 16 + c15) * 32 + ((g ^ cr) * 8)];
            }
            for (int mi = 0; mi < 4; mi++)
                for (int ni = 0; ni < 4; ni++)
                    acc[mi][ni] = __builtin_amdgcn_mfma_f32_16x16x32_bf16(
                        af[mi], bf[ni], acc[mi][ni], 0, 0, 0);
        }
        vmwait0();        // drains stage(st+1): latency already overlapped by compute above
        __syncthreads();
    }

    for (int mi = 0; mi < 4; mi++) {
        int r = m0 + wm * 64 + mi * 16 + g * 4;
        int batch = r >> 11, nbase = r & 2047;   // nbase = slot for Q-region tiles
        for (int ni = 0; ni < 4; ni++) {
            int cN = n0 + wn * 64 + ni * 16 + c15;
            int p = cN >> 8, h = (cN >> 6) & 3, d = cN & 63;
            size_t hb = (size_t)((branch * 4 + batch) * 4 + h) * 131072;
            f32x4 vv = acc[mi][ni];
            if (p == 2) {
                s16x4 pk;
                for (int rg = 0; rg < 4; rg++) pk[rg] = (short)f2b(vv[rg]);
                int pos = nbase & 31;
                int slot = ((pos & 15) >> 2) * 8 + ((pos >> 4) << 2);
                *(s16x4*)(Vt + hb + (size_t)d * 2048 + (nbase & ~31) + slot) = pk;
            } else if (p == 0) {
                for (int rg = 0; rg < 4; rg++)
                    Qo[hb + (size_t)(nbase + rg) * 64 + d] = f2b(vv[rg] * QSCALE);
            } else {
                for (int rg = 0; rg < 4; rg++)
                    Ko[hb + (size_t)(nbase + rg) * 64 + d] = f2b(vv[rg]);
            }
        }
    }
}

// ---------------- flash attention (R15-proven): slot-direct Q, LDS-staged K/V, + T5 setprio ----------------
#define ATTN_STEP(KF, VF) do {                                                              \
    __builtin_amdgcn_s_setprio(1);                                                          \
    _Pragma("unroll")                                                                       \
    for (int s = 0; s < 2; s++) {                                                           \
        f32x4 sa0 = __builtin_amdgcn_mfma_f32_16x16x32_bf16(KF[0][0], qf[s][0], z4, 0, 0, 0); \
        sa0 = __builtin_amdgcn_mfma_f32_16x16x32_bf16(KF[0][1], qf[s][1], sa0, 0, 0, 0);    \
        f32x4 sa1 = __builtin_amdgcn_mfma_f32_16x16x32_bf16(KF[1][0], qf[s][0], z4, 0, 0, 0); \
        sa1 = __builtin_amdgcn_mfma_f32_16x16x32_bf16(KF[1][1], qf[s][1], sa1, 0, 0, 0);    \
        float q0 = fexp2(sa0[0]), q1 = fexp2(sa0[1]);                                       \
        float q2 = fexp2(sa0[2]), q3 = fexp2(sa0[3]);                                       \
        float q4 = fexp2(sa1[0]), q5 = fexp2(sa1[1]);                                       \
        float q6 = fexp2(sa1[2]), q7 = fexp2(sa1[3]);                                       \
        lsp[s] += ((q0 + q1) + (q2 + q3)) + ((q4 + q5) + (q6 + q7));                        \
        u32x4 pw;                                                                           \
        pw[0] = cvtpk(q0, q1); pw[1] = cvtpk(q2, q3);                                       \
        pw[2] = cvtpk(q4, q5); pw[3] = cvtpk(q6, q7);                                       \
        union { u32x4 w; s16x8 h; } pu; pu.w = pw;                                          \
        s16x8 pb = pu.h;                                                                    \
        _Pragma("unroll")                                                                   \
        for (int dt = 0; dt < 4; dt++)                                                      \
            oac[s][dt] = __builtin_amdgcn_mfma_f32_16x16x32_bf16(VF[dt], pb, oac[s][dt], 0, 0, 0); \
    }                                                                                       \
    __builtin_amdgcn_s_setprio(0);                                                          \
} while (0)

#define STAGE(B, T) do {                                                  \
    const unsigned char* _ks = Ksrc + (size_t)(T) * 8192;                 \
    const unsigned char* _vs = Vsrc + (size_t)(T) * 128;                  \
    unsigned char* _kd = &lds[(B) * 16384 + w * 2048];                    \
    unsigned char* _vd = &lds[(B) * 16384 + 8192 + w * 2048];             \
    GLL(_ks, _kd); GLL(_ks + 1024, _kd + 1024);                           \
    GLL(_vs, _vd); GLL(_vs + 32768, _vd + 1024);                          \
} while (0)

#define TILE_STEP(B) do {                                                               \
    const unsigned char* _KL = &lds[(B) * 16384];                                       \
    const unsigned char* _VL = &lds[(B) * 16384 + 8192];                                \
    s16x8 kf[2][2], vf[4];                                                              \
    _Pragma("unroll")                                                                   \
    for (int t = 0; t < 2; t++)                                                         \
        _Pragma("unroll")                                                               \
        for (int h = 0; h < 2; h++)                                                     \
            kf[t][h] = *(const s16x8*)(_KL + (t * 16 + c) * 128 + (((h * 4 + g) ^ cx) * 16)); \
    _Pragma("unroll")                                                                   \
    for (int dt = 0; dt < 4; dt++)                                                      \
        vf[dt] = *(const s16x8*)(_VL + (dt * 16 + c) * 128 + ((g ^ cx) * 16));          \
    ATTN_STEP(kf, vf);                                                                  \
    _Pragma("unroll")                                                                   \
    for (int t = 0; t < 2; t++)                                                         \
        _Pragma("unroll")                                                               \
        for (int h = 0; h < 2; h++)                                                     \
            kf[t][h] = *(const s16x8*)(_KL + ((t + 2) * 16 + c) * 128 + (((h * 4 + g) ^ cx) * 16)); \
    _Pragma("unroll")                                                                   \
    for (int dt = 0; dt < 4; dt++)                                                      \
        vf[dt] = *(const s16x8*)(_VL + (dt * 16 + c) * 128 + (((4 + g) ^ cx) * 16));    \
    ATTN_STEP(kf, vf);                                                                  \
} while (0)

__global__ __launch_bounds__(256, 4) void attn_kernel(const u16* __restrict__ Qg,
                                                      const u16* __restrict__ Kg,
                                                      const u16* __restrict__ Vg,
                                                      const int* __restrict__ cnt,
                                                      u16* __restrict__ Og) {
    __shared__ unsigned char lds[32768];
    const int tid = threadIdx.x;
    const int w = tid >> 6, lane = tid & 63;
    const int b = blockIdx.x;
    const int j = b >> 3;
    const int inst = (b & 7) * 6 + (j % 6);   // XCD-pinned instance
    const int branch = inst >> 4, batch = (inst >> 2) & 3, h = inst & 3;
    const int cb = branch * 4 + batch;
    const int count = min(2048, cnt[cb]);
    const int qbase = (j / 6) * 128;
    if (qbase >= count) return;               // uniform whole-block exit
    const int qt = (j / 6) * 4 + w;           // q-tile of 32 compacted slots
    const int g = lane >> 4, c = lane & 15;
    const int cx = c & 7;
    const u16* Qh = Qg + (size_t)inst * 131072;

    f32x4 z4 = {0.f, 0.f, 0.f, 0.f};
    s16x8 qf[2][2];
    #pragma unroll
    for (int kk = 0; kk < 2; kk++) {
        qf[0][kk] = *(const s16x8*)(Qh + (size_t)(qt * 32 + c) * 64 + kk * 32 + g * 8);
        qf[1][kk] = *(const s16x8*)(Qh + (size_t)(qt * 32 + 16 + c) * 64 + kk * 32 + g * 8);
    }

    f32x4 oac[2][4];
    #pragma unroll
    for (int s = 0; s < 2; s++)
        #pragma unroll
        for (int dt = 0; dt < 4; dt++) oac[s][dt] = z4;
    float lsp[2] = {0.f, 0.f};

    const int swz = (((lane & 7) ^ ((lane >> 3) & 7)) << 4);
    const unsigned char* Ksrc = (const unsigned char*)(Kg + (size_t)inst * 131072)
                                + w * 2048 + ((lane >> 3) << 7) + swz;
    const unsigned char* Vsrc = (const unsigned char*)(Vg + (size_t)inst * 131072)
                                + (size_t)w * 65536 + ((lane >> 3) << 12) + swz;

    STAGE(0, 0);
    vmwait0();
    __syncthreads();
    for (int t2 = 0; t2 < 32; t2++) {
        int cur = t2 & 1;
        if (t2 + 1 < 32) STAGE(cur ^ 1, t2 + 1);
        TILE_STEP(cur);
        vmwait0();
        __syncthreads();
    }

    // write ALL 128 slots of this block (slots >= count hold duplicated real rows)
    #pragma unroll
    for (int s = 0; s < 2; s++) {
        float ls = lsp[s];
        ls += __shfl_xor(ls, 16);
        ls += __shfl_xor(ls, 32);
        float inv = 1.0f / ls;
        int slot = qt * 32 + s * 16 + c;
        u16* dst = Og + ((size_t)cb * 2048 + slot) * 256 + h * 64;
        #pragma unroll
        for (int dt = 0; dt < 4; dt++) {
            s16x4 ob;
            for (int rg = 0; rg < 4; rg++) ob[rg] = (short)f2b(oac[s][dt][rg] * inv);
            *(s16x4*)(dst + dt * 16 + g * 4) = ob;
        }
    }
}

// ---------------- proj GEMM: contiguous compacted rows, masked scatter ----------------
__global__ __launch_bounds__(256) void proj_gemm_kernel(const u16* __restrict__ Oall,
                                                        const u16* __restrict__ Wpt_all,
                                                        const u16* __restrict__ perm,
                                                        const int* __restrict__ cnt,
                                                        const int* __restrict__ startA,
                                                        const float* __restrict__ bp1,
                                                        const float* __restrict__ bp2,
                                                        const float* __restrict__ bp3,
                                                        float* __restrict__ out) {
    __shared__ u16 As[128 * 64];
    __shared__ u16 Bs[128 * 64];
    const int tid = threadIdx.x;
    const int lane = tid & 63, w = tid >> 6, wm = w >> 1, wn = w & 1;
    const int g = lane >> 4, c15 = lane & 15;
    const int cx = c15 & 7;
    const int branch = blockIdx.z;
    const int m0 = blockIdx.y * 128, n0 = blockIdx.x * 128;
    const int batch = m0 >> 11;
    const int cb = branch * 4 + batch;
    const int count = min(2048, cnt[cb]);
    const int pbase = m0 & 2047;
    if (pbase >= count) return;
    const u16* A = Oall + (size_t)branch * 8192 * 256;
    const u16* Bt = Wpt_all + (size_t)branch * 196608;
    const float* bp = (branch == 0) ? bp1 : ((branch == 1) ? bp2 : bp3);

    const int l8 = lane >> 3;
    const int ch = (lane & 7) ^ l8;
    const u16* Asrc = A + (size_t)(m0 + w * 32 + l8) * 256 + ch * 8;
    const u16* Bsrc = Bt + (size_t)(n0 + w * 32 + l8) * 256 + ch * 8;
    u16* AsW = As + w * 2048;
    u16* BsW = Bs + w * 2048;

    f32x4 z4 = {0.f, 0.f, 0.f, 0.f};
    f32x4 acc[4][4];
    for (int mi = 0; mi < 4; mi++)
        for (int ni = 0; ni < 4; ni++) acc[mi][ni] = z4;

    for (int k0 = 0; k0 < 256; k0 += 64) {
        __syncthreads();
        #pragma unroll
        for (int it = 0; it < 4; it++) {
            GLL(Asrc + (size_t)(it * 8) * 256 + k0, AsW + it * 512);
            GLL(Bsrc + (size_t)(it * 8) * 256 + k0, BsW + it * 512);
        }
        vmwait0();
        __syncthreads();
        #pragma unroll
        for (int kk = 0; kk < 2; kk++) {
            s16x8 af[4], bf[4];
            #pragma unroll
            for (int i = 0; i < 4; i++) {
                af[i] = *(const s16x8*)&As[(wm * 64 + i * 16 + c15) * 64 + (((kk * 4 + g) ^ cx) * 8)];
                bf[i] = *(const s16x8*)&Bs[(wn * 64 + i * 16 + c15) * 64 + (((kk * 4 + g) ^ cx) * 8)];
            }
            for (int mi = 0; mi < 4; mi++)
                for (int ni = 0; ni < 4; ni++)
                    acc[mi][ni] = __builtin_amdgcn_mfma_f32_16x16x32_bf16(
                        af[mi], bf[ni], acc[mi][ni], 0, 0, 0);
        }
    }

    const u16* ci = perm + batch * 2048 + startA[cb];
    for (int mi = 0; mi < 4; mi++) {
        int r = pbase + wm * 64 + mi * 16 + g * 4;
        for (int ni = 0; ni < 4; ni++) {
            int cN = n0 + wn * 64 + ni * 16 + c15;
            float bj = bp[cN];
            f32x4 v = acc[mi][ni];
            for (int rg = 0; rg < 4; rg++) {
                int slot = r + rg;
                if (slot < count) {
                    int t = batch * 2048 + (ci[slot] & 2047);
                    float wv = v[rg] + bj;
                    out[(size_t)t * 768 + cN] = wv;                 // xo
                    out[6291456u + (size_t)t * 768 + cN] = wv;      // xd
                }
            }
        }
    }
}

extern "C" void kernel_launch(void* const* d_in, const int* in_sizes, int n_in,
                              void* d_out, int out_size, void* d_ws, size_t ws_size,
                              hipStream_t stream) {
    const float* x   = (const float*)d_in[0];
    const float* Wq1 = (const float*)d_in[1];
    const float* Wq2 = (const float*)d_in[2];
    const float* Wq3 = (const float*)d_in[3];
    const float* Wp1 = (const float*)d_in[4];
    const float* bp1 = (const float*)d_in[5];
    const float* Wp2 = (const float*)d_in[6];
    const float* bp2 = (const float*)d_in[7];
    const float* Wp3 = (const float*)d_in[8];
    const float* bp3 = (const float*)d_in[9];
    const float* Wg  = (const float*)d_in[10];
    float* out = (float*)d_out;

    char* ws = (char*)d_ws;
    u16* xb    = (u16*)(ws + 0);          // 12582912 B
    u16* wqt   = (u16*)(ws + 12582912);   // 3538944 B
    u16* wpt   = (u16*)(ws + 16121856);   // 1179648 B
    u16* Qb    = (u16*)(ws + 17301504);   // 12582912 B (48 x [2048 slots][64], pre-scaled, compacted)
    u16* Kb    = (u16*)(ws + 29884416);   // 12582912 B
    u16* Vtb   = (u16*)(ws + 42467328);   // 12582912 B (48 x [64][2048], slot-remapped)
    u16* Ob    = (u16*)(ws + 55050240);   // 12582912 B (12 x [2048][256], compacted rows)
    u16* perm  = (u16*)(ws + 67633152);   // 16384 B (4 x 2048 u16)
    int* cnt   = (int*)(ws + 67649536);   // 48 B
    int* start = (int*)(ws + 67649600);   // 48 B
    u8*  kArr  = (u8*) (ws + 67649664);   // 8192 B  -> end 67657856

    prolog_kernel<<<4352, 256, 0, stream>>>(x, Wg, xb, kArr, out,
                                            Wq1, Wq2, Wq3, Wp1, Wp2, Wp3, wqt, wpt);
    compact_kernel<<<4, 64, 0, stream>>>(kArr, perm, cnt, start);
    qkv_gemm_kernel<<<1152, 256, 0, stream>>>(xb, wqt, perm, cnt, start, Qb, Kb, Vtb);
    attn_kernel<<<768, 256, 0, stream>>>(Qb, Kb, Vtb, cnt, Ob);
    proj_gemm_kernel<<<dim3(6, 64, 3), 256, 0, stream>>>(Ob, wpt, perm, cnt, start, bp1, bp2, bp3, out);
}